// Round 8
// baseline (99.672 us; speedup 1.0000x reference)
//
#include <hip/hip_runtime.h>

// Ca_Aware_Embedder: distogram one-hot -> linear embed, fused.
// out[pair, c] = W[c, bin(pair)] + b[c], where bin() may be "none" -> b[c].
// Write-bandwidth-bound: 1024*1024*128 fp32 = 536.9 MB out. Demonstrated
// plain-store ceiling (rocclr fill): ~6.75 TB/s -> 79.5 us + ~4 us launch.
// R7 = 94.8 us (5.66 TB/s, 84% of fill rate).
//
// R8: 1KB-contiguous stores. R7's wave split lanes 0-31 / 32-63 across pairs
// 32KB apart -> each store inst touched TWO 512B segments. Now wave wv owns
// 128 consecutive pairs; half h handles pairs 2m+h, so one store inst covers
// adjacent pairs {P, P+1} = contiguous 1KB (same as the 84%-of-peak fill).
// Bin bytes parity-split in LDS so each half reads its 8 bins per group with
// one broadcast ds_read_b64. Plain stores (R6: nt harmful); 2048 blocks
// (R5: max occupancy needed).

typedef float f32x4 __attribute__((ext_vector_type(4)));

constexpr int N_RES = 1024;
constexpr int C_Z = 128;
constexpr int NO_BINS = 15;
constexpr int THREADS = 256;
constexpr int BLOCKS = 2048;                               // 8 blocks/CU
constexpr int PAIRS_PER_BLOCK = (N_RES * N_RES) / BLOCKS;  // 512 (half a row)
constexpr float INF_UPPER = 100000000.0f;

__global__ __launch_bounds__(THREADS) void ca_embedder_kernel(
    const float* __restrict__ x,   // [N_RES, 3]
    const float* __restrict__ W,   // [C_Z, NO_BINS]
    const float* __restrict__ b,   // [C_Z]
    float* __restrict__ out)       // [N_RES, N_RES, C_Z]
{
    __shared__ float Wt[NO_BINS + 1][C_Z];       // Wt[k][c] = W[c][k] + b[c]; row 15 = b
    __shared__ unsigned char sbin8[PAIRS_PER_BLOCK];  // parity-split: [p&1][p>>1]

    // Stage W^T (+ b) into LDS once per block.
    for (int idx = threadIdx.x; idx < C_Z * NO_BINS; idx += THREADS) {
        int c = idx / NO_BINS;
        int k = idx - c * NO_BINS;
        Wt[k][c] = W[idx] + b[c];
    }
    if (threadIdx.x < C_Z) {
        Wt[NO_BINS][threadIdx.x] = b[threadIdx.x];
    }

    const size_t base = (size_t)blockIdx.x * PAIRS_PER_BLOCK;
    // All 512 pairs of this block share row i (512 divides 1024).
    const int i = (int)(base >> 10);
    const float xi0 = x[3 * i + 0];
    const float xi1 = x[3 * i + 1];
    const float xi2 = x[3 * i + 2];
    const int j0 = (int)(base & (N_RES - 1));

    // Bin pre-pass: 512 bins, 2 per thread, exact reference semantics.
    // Stored parity-split so each wave-half later reads contiguous bytes.
    for (int p = threadIdx.x; p < PAIRS_PER_BLOCK; p += THREADS) {
        const int j = j0 + p;
        const float dx = xi0 - x[3 * j + 0];
        const float dy = xi1 - x[3 * j + 1];
        const float dz = xi2 - x[3 * j + 2];
        const float d = dx * dx + dy * dy + dz * dz;

        int bin = NO_BINS;  // "no bin" -> b row
#pragma unroll
        for (int k = 0; k < NO_BINS; ++k) {
            const float blo = 3.25f + 1.25f * (float)k;
            const float lo = blo * blo;
            const float bhi = 3.25f + 1.25f * (float)(k + 1);
            const float hi = (k == NO_BINS - 1) ? INF_UPPER : bhi * bhi;
            if (d > lo && d < hi) bin = k;   // strict, matches reference
        }
        sbin8[(p & 1) * (PAIRS_PER_BLOCK / 2) + (p >> 1)] = (unsigned char)bin;
    }
    __syncthreads();

    // Streaming loop. Wave wv owns pairs [wv*128, wv*128+128). Half h covers
    // pairs 2m+h -> each store wave-inst writes adjacent pairs {P,P+1} = 1KB.
    const int wv = threadIdx.x >> 6;            // wave, 0..3
    const int half = (threadIdx.x >> 5) & 1;    // wave half, 0/1
    const int lane31 = threadIdx.x & 31;        // channel quad, 0..31

    f32x4* __restrict__ po =
        reinterpret_cast<f32x4*>(out) + (base + (size_t)(wv * 128 + half)) * (C_Z / 4) + lane31;
    const unsigned char* __restrict__ mybins =
        &sbin8[half * (PAIRS_PER_BLOCK / 2) + wv * 64];

    for (int g = 0; g < 8; ++g) {
        const uint2 w2 = *reinterpret_cast<const uint2*>(&mybins[g * 8]);
#pragma unroll
        for (int k = 0; k < 8; ++k) {
            const unsigned int w = (k < 4) ? w2.x : w2.y;         // static select
            const int bin = (w >> ((k & 3) * 8)) & 0xFF;
            const f32x4 v = *reinterpret_cast<const f32x4*>(&Wt[bin][lane31 * 4]);
            po[(size_t)(g * 8 + k) * 2 * (C_Z / 4)] = v;          // pair 2m+half
        }
    }
}

extern "C" void kernel_launch(void* const* d_in, const int* in_sizes, int n_in,
                              void* d_out, int out_size, void* d_ws, size_t ws_size,
                              hipStream_t stream) {
    const float* x = (const float*)d_in[0];
    const float* W = (const float*)d_in[1];
    const float* b = (const float*)d_in[2];
    float* out = (float*)d_out;

    ca_embedder_kernel<<<dim3(BLOCKS), dim3(THREADS), 0, stream>>>(x, W, b, out);
}

// Round 9
// 95.006 us; speedup vs baseline: 1.0491x; 1.0491x over previous
//
#include <hip/hip_runtime.h>

// Ca_Aware_Embedder: distogram one-hot -> linear embed, fused.
// out[pair, c] = W[c, bin(pair)] + b[c], where bin() may be "none" -> b[c].
// Write-bandwidth-bound: 1024*1024*128 fp32 = 536.9 MB out. Demonstrated
// plain-store ceiling (rocclr fill): ~6.75 TB/s -> 79.5 us + ~4 us launch.
// Ladder: R4 101.4 -> R6 99.0 (plain>nt) -> R7 94.8 (byte bins, b64 feed).
// R8 (1KB-contig stores) REGRESSED to 99.7 -> store micro-shape not the tax.
//
// R9: R7 exactly, plus: hoist ALL 8 bin-words per thread into registers
// before the store loop (static-indexed, no scratch). Steady loop is a pure
// {extract bin, ds_read_b128 Wt, plain dwordx4 store} stream with no
// periodic ds_read_b64 dependency fence.

typedef float f32x4 __attribute__((ext_vector_type(4)));

constexpr int N_RES = 1024;
constexpr int C_Z = 128;
constexpr int NO_BINS = 15;
constexpr int THREADS = 256;
constexpr int BLOCKS = 2048;                               // 8 blocks/CU (R5: max occupancy needed)
constexpr int PAIRS_PER_BLOCK = (N_RES * N_RES) / BLOCKS;  // 512 (half a row)
constexpr float INF_UPPER = 100000000.0f;

__global__ __launch_bounds__(THREADS) void ca_embedder_kernel(
    const float* __restrict__ x,   // [N_RES, 3]
    const float* __restrict__ W,   // [C_Z, NO_BINS]
    const float* __restrict__ b,   // [C_Z]
    float* __restrict__ out)       // [N_RES, N_RES, C_Z]
{
    __shared__ float Wt[NO_BINS + 1][C_Z];       // Wt[k][c] = W[c][k] + b[c]; row 15 = b
    __shared__ unsigned char sbin8[PAIRS_PER_BLOCK];

    // Stage W^T (+ b) into LDS once per block.
    for (int idx = threadIdx.x; idx < C_Z * NO_BINS; idx += THREADS) {
        int c = idx / NO_BINS;
        int k = idx - c * NO_BINS;
        Wt[k][c] = W[idx] + b[c];
    }
    if (threadIdx.x < C_Z) {
        Wt[NO_BINS][threadIdx.x] = b[threadIdx.x];
    }

    const size_t base = (size_t)blockIdx.x * PAIRS_PER_BLOCK;
    // All 512 pairs of this block share row i (512 divides 1024).
    const int i = (int)(base >> 10);
    const float xi0 = x[3 * i + 0];
    const float xi1 = x[3 * i + 1];
    const float xi2 = x[3 * i + 2];
    const int j0 = (int)(base & (N_RES - 1));

    // Bin pre-pass: 512 bins, 2 per thread, exact reference semantics.
    for (int p = threadIdx.x; p < PAIRS_PER_BLOCK; p += THREADS) {
        const int j = j0 + p;
        const float dx = xi0 - x[3 * j + 0];
        const float dy = xi1 - x[3 * j + 1];
        const float dz = xi2 - x[3 * j + 2];
        const float d = dx * dx + dy * dy + dz * dz;

        int bin = NO_BINS;  // "no bin" -> b row
#pragma unroll
        for (int k = 0; k < NO_BINS; ++k) {
            const float blo = 3.25f + 1.25f * (float)k;
            const float lo = blo * blo;
            const float bhi = 3.25f + 1.25f * (float)(k + 1);
            const float hi = (k == NO_BINS - 1) ? INF_UPPER : bhi * bhi;
            if (d > lo && d < hi) bin = k;   // strict, matches reference
        }
        sbin8[p] = (unsigned char)bin;
    }
    __syncthreads();

    // Hoist all 64 bin bytes (8 uint2 words) for this thread's pair-group
    // into registers up front — static indexing only (stays in VGPRs).
    const int lp = threadIdx.x >> 5;     // pair-group, 0..7 (owns pairs lp*64..lp*64+63)
    const int lane = threadIdx.x & 31;   // channel quad, 0..31

    uint2 bw[8];
#pragma unroll
    for (int g = 0; g < 8; ++g) {
        bw[g] = *reinterpret_cast<const uint2*>(&sbin8[lp * 64 + g * 8]);
    }

    f32x4* __restrict__ po =
        reinterpret_cast<f32x4*>(out) + (base + (size_t)lp * 64) * (C_Z / 4) + lane;

    // Pure streaming loop: 64x {extract bin, ds_read_b128 Wt row, store}.
#pragma unroll
    for (int g = 0; g < 8; ++g) {
#pragma unroll
        for (int k = 0; k < 8; ++k) {
            const unsigned int w = (k < 4) ? bw[g].x : bw[g].y;   // static select
            const int bin = (w >> ((k & 3) * 8)) & 0xFF;
            const f32x4 v = *reinterpret_cast<const f32x4*>(&Wt[bin][lane * 4]);
            po[(size_t)(g * 8 + k) * (C_Z / 4)] = v;
        }
    }
}

extern "C" void kernel_launch(void* const* d_in, const int* in_sizes, int n_in,
                              void* d_out, int out_size, void* d_ws, size_t ws_size,
                              hipStream_t stream) {
    const float* x = (const float*)d_in[0];
    const float* W = (const float*)d_in[1];
    const float* b = (const float*)d_in[2];
    float* out = (float*)d_out;

    ca_embedder_kernel<<<dim3(BLOCKS), dim3(THREADS), 0, stream>>>(x, W, b, out);
}